// Round 1
// baseline (123.823 us; speedup 1.0000x reference)
//
#include <hip/hip_runtime.h>
#include <hip/hip_bf16.h>

#define BB 256
#define LL 512
#define FF 64
#define NIDS 2000

// workspace layout in 4-byte elements
#define WS_TABLE 0                  // 513*64 floats
#define WS_PIDX  32832              // 2*BB*LL ints   (per-row pair index)
#define WS_PKEY  (32832 + 262144)   // 2*BB*LL ints   (packed (ca | cb<<10))
#define WS_PMULT (32832 + 524288)   // 2*BB*LL ints   (pair multiplicity)
#define WS_NPAIR (32832 + 786432)   // 2*BB ints

// ---------------------------------------------------------------------------
// Table: T(c)[g] = sum_f relu(c*w1[f]+b1[f]) * w2[f][g] + b2[g], c in [0,512]
// feat(row) = T(c_a) + T(c_b)  (b2 folded in: sum over 2 channels = +2*b2)
// ---------------------------------------------------------------------------
__global__ __launch_bounds__(64) void k_table(
    const float* __restrict__ w1, const float* __restrict__ b1,
    const float* __restrict__ w2, const float* __restrict__ b2,
    float* __restrict__ table) {
  int c = blockIdx.x, f = threadIdx.x;
  __shared__ float h[64];
  h[f] = fmaxf((float)c * w1[f] + b1[f], 0.f);
  __syncthreads();
  float acc = b2[f];
#pragma unroll
  for (int g = 0; g < 64; ++g) acc += h[g] * w2[g * 64 + f];
  table[c * 64 + f] = acc;
}

// ---------------------------------------------------------------------------
// Per-batch: LDS histograms of src/dst ids, then dedup (ca,cb) pairs per side
// via LDS open-addressing hash. Outputs pair list + multiplicity + per-row idx.
// ---------------------------------------------------------------------------
__global__ __launch_bounds__(256) void k_dedup(
    const int* __restrict__ src, const int* __restrict__ dst,
    int* __restrict__ pidx, int* __restrict__ pkey,
    int* __restrict__ pmult, int* __restrict__ npair) {
  int b = blockIdx.x, tid = threadIdx.x;
  __shared__ int hs[NIDS], hd[NIDS];
  __shared__ int hkey[1024], hmult[1024], hidx[1024];
  __shared__ int np;
  for (int i = tid; i < NIDS; i += 256) { hs[i] = 0; hd[i] = 0; }
  __syncthreads();
  const int* s = src + b * LL;
  const int* d = dst + b * LL;
  int sid0 = s[tid], sid1 = s[tid + 256];
  int did0 = d[tid], did1 = d[tid + 256];
  atomicAdd(&hs[sid0], 1); atomicAdd(&hs[sid1], 1);
  atomicAdd(&hd[did0], 1); atomicAdd(&hd[did1], 1);
  __syncthreads();
  for (int side = 0; side < 2; ++side) {
    for (int i = tid; i < 1024; i += 256) { hkey[i] = -1; hmult[i] = 0; }
    if (tid == 0) np = 0;
    __syncthreads();
    int slot[2];
    for (int r = 0; r < 2; ++r) {
      int id = (side == 0) ? (r ? sid1 : sid0) : (r ? did1 : did0);
      int ca = 0, cb = 0;
      if (id != 0) {
        if (side == 0) { ca = hs[id]; cb = hd[id]; }
        else           { ca = hd[id]; cb = hs[id]; }
      }
      int key = ca | (cb << 10);
      int h = (int)(((unsigned)key * 2654435761u) >> 22) & 1023;
      while (true) {
        int old = atomicCAS(&hkey[h], -1, key);
        if (old == -1 || old == key) break;
        h = (h + 1) & 1023;
      }
      atomicAdd(&hmult[h], 1);
      slot[r] = h;
    }
    __syncthreads();
    for (int i = tid; i < 1024; i += 256) {
      if (hkey[i] != -1) {
        int idx = atomicAdd(&np, 1);
        hidx[i] = idx;
        pkey [(side * BB + b) * LL + idx] = hkey[i];
        pmult[(side * BB + b) * LL + idx] = hmult[i];
      }
    }
    __syncthreads();
    pidx[(side * BB + b) * LL + tid]       = hidx[slot[0]];
    pidx[(side * BB + b) * LL + tid + 256] = hidx[slot[1]];
    if (tid == 0) npair[side * BB + b] = np;
    __syncthreads();
  }
}

// ---------------------------------------------------------------------------
// Per (batch, direction): linear cross-attention + LN on DEDUPED pair rows,
// then scatter output rows to the 512 sequence positions.
//   M[d][e] = sum_j n_j * exp(k_j[d]) * v_j[e] / sum_j n_j * exp(k_j[d])
//   G = M @ Wo ;  out_row(i) = LN(feat_i + (softmax(feat_i@Wq)/8) @ G + bo)
// Weight columns held in VGPRs; feature rows broadcast from wave-local LDS.
// ---------------------------------------------------------------------------
__global__ __launch_bounds__(256, 2) void k_attn(
    const float* __restrict__ table,
    const int* __restrict__ pidx, const int* __restrict__ pkey,
    const int* __restrict__ pmult, const int* __restrict__ npair,
    const float* __restrict__ Wq, const float* __restrict__ Wk,
    const float* __restrict__ Wv, const float* __restrict__ Wo,
    const float* __restrict__ bo, const float* __restrict__ lng,
    const float* __restrict__ lnb, float* __restrict__ out) {
  int bd = blockIdx.x;
  int b = bd >> 1, dir = bd & 1;
  int tid = threadIdx.x, tx = tid & 63, ty = tid >> 6;

  __shared__ float featb[4][64];
  __shared__ float pbuf[4][64];
  __shared__ float vbuf[4][64];
  __shared__ float sred[4][64];
  __shared__ float M[64 * 65];   // +1 pad: conflict-free strided access
  __shared__ float G[64 * 65];
  __shared__ float wS[64 * 64];  // Wo staging, then rowout chunk
  __shared__ int pidxl[512];
  __shared__ int xkeyb[512];
  __shared__ int ckeyb[512];
  __shared__ int cmultb[512];

  int xs = dir, cs = 1 - dir;
  for (int i = tid; i < 512; i += 256) {
    pidxl[i]  = pidx [(xs * BB + b) * LL + i];
    xkeyb[i]  = pkey [(xs * BB + b) * LL + i];
    ckeyb[i]  = pkey [(cs * BB + b) * LL + i];
    cmultb[i] = pmult[(cs * BB + b) * LL + i];
  }
  int Pc = npair[cs * BB + b];
  int Px = npair[xs * BB + b];

  // Wk / Wv columns (col = tx) in registers
  float wcA[64], wcB[64];
#pragma unroll
  for (int f = 0; f < 64; ++f) { wcA[f] = Wk[f * 64 + tx]; wcB[f] = Wv[f * 64 + tx]; }
  float macc[16];
#pragma unroll
  for (int e = 0; e < 16; ++e) macc[e] = 0.f;
  float sacc = 0.f;
  __syncthreads();  // staged LDS ready

  // ---- Phase A: accumulate column sums + M_raw over ctx pairs (4/group) ----
  for (int j0 = 0; j0 < Pc; j0 += 4) {
    int j = j0 + ty;
    if (j < Pc) {
      int key = ckeyb[j];
      int ca = key & 1023, cb = key >> 10;
      featb[ty][tx] = table[ca * 64 + tx] + table[cb * 64 + tx];
      float kr = 0.f, vr = 0.f;
      const float4* fb4 = (const float4*)(&featb[ty][0]);
#pragma unroll
      for (int f4 = 0; f4 < 16; ++f4) {
        float4 fv = fb4[f4];
        kr += fv.x * wcA[4 * f4] + fv.y * wcA[4 * f4 + 1] + fv.z * wcA[4 * f4 + 2] + fv.w * wcA[4 * f4 + 3];
        vr += fv.x * wcB[4 * f4] + fv.y * wcB[4 * f4 + 1] + fv.z * wcB[4 * f4 + 2] + fv.w * wcB[4 * f4 + 3];
      }
      float p = __expf(kr) * (float)cmultb[j];  // |kr| ~ O(10): no max-sub needed
      sacc += p;
      pbuf[ty][tx] = p;
      vbuf[ty][tx] = vr;
    }
    __syncthreads();
    int jn = min(4, Pc - j0);
    int e0 = ty * 16;
    for (int jj = 0; jj < jn; ++jj) {
      float pg = pbuf[jj][tx];
      const float4* vb4 = (const float4*)(&vbuf[jj][e0]);
#pragma unroll
      for (int q = 0; q < 4; ++q) {
        float4 vv = vb4[q];
        macc[4 * q]     += pg * vv.x; macc[4 * q + 1] += pg * vv.y;
        macc[4 * q + 2] += pg * vv.z; macc[4 * q + 3] += pg * vv.w;
      }
    }
    __syncthreads();
  }
  sred[ty][tx] = sacc;
  __syncthreads();
  float sg = sred[0][tx] + sred[1][tx] + sred[2][tx] + sred[3][tx];
  float inv = 1.f / sg;
  int e0 = ty * 16;
#pragma unroll
  for (int e = 0; e < 16; ++e) M[tx * 65 + e0 + e] = macc[e] * inv;
  for (int i = tid; i < 4096; i += 256) wS[i] = Wo[i];
  __syncthreads();

  // ---- G = M @ Wo ----
#pragma unroll
  for (int e = 0; e < 16; ++e) macc[e] = 0.f;
  for (int e = 0; e < 64; ++e) {
    float m = M[tx * 65 + e];
    const float4* wo4 = (const float4*)(&wS[e * 64 + e0]);
#pragma unroll
    for (int q = 0; q < 4; ++q) {
      float4 w4 = wo4[q];
      macc[4 * q]     += m * w4.x; macc[4 * q + 1] += m * w4.y;
      macc[4 * q + 2] += m * w4.z; macc[4 * q + 3] += m * w4.w;
    }
  }
#pragma unroll
  for (int e = 0; e < 16; ++e) G[tx * 65 + e0 + e] = macc[e];
#pragma unroll
  for (int f = 0; f < 64; ++f) wcA[f] = Wq[f * 64 + tx];  // reuse regs for Wq
  float bov = bo[tx], lg = lng[tx], lb = lnb[tx];
  __syncthreads();  // G ready; wS now free for rowout chunks

  // ---- Phase B: per distinct x pair -> output row; chunked scatter ----
  for (int i0 = 0; i0 < Px; i0 += 64) {
    int cN = min(64, Px - i0);
    for (int jj = ty; jj < cN; jj += 4) {
      int key = xkeyb[i0 + jj];
      int ca = key & 1023, cb = key >> 10;
      float fv = table[ca * 64 + tx] + table[cb * 64 + tx];
      featb[ty][tx] = fv;
      float qr = 0.f;
      const float4* fb4 = (const float4*)(&featb[ty][0]);
#pragma unroll
      for (int f4 = 0; f4 < 16; ++f4) {
        float4 f4v = fb4[f4];
        qr += f4v.x * wcA[4 * f4] + f4v.y * wcA[4 * f4 + 1] + f4v.z * wcA[4 * f4 + 2] + f4v.w * wcA[4 * f4 + 3];
      }
      float p = __expf(qr);
      float sum = p;
#pragma unroll
      for (int off = 32; off >= 1; off >>= 1) sum += __shfl_xor(sum, off, 64);
      float qh = p / sum * 0.125f;  // softmax * F^-0.5
      pbuf[ty][tx] = qh;
      float at = 0.f;
#pragma unroll
      for (int dd = 0; dd < 64; ++dd) at += pbuf[ty][dd] * G[dd * 65 + tx];
      float r = fv + at + bov;
      float mu = r;
#pragma unroll
      for (int off = 32; off >= 1; off >>= 1) mu += __shfl_xor(mu, off, 64);
      mu *= (1.f / 64.f);
      float dv = r - mu;
      float var = dv * dv;
#pragma unroll
      for (int off = 32; off >= 1; off >>= 1) var += __shfl_xor(var, off, 64);
      var *= (1.f / 64.f);
      wS[jj * 64 + tx] = dv * rsqrtf(var + 1e-5f) * lg + lb;
    }
    __syncthreads();
    const float4* w4 = (const float4*)wS;
    float4* out4 = (float4*)(out + (size_t)(dir * BB + b) * LL * 64);
    for (int idx = tid; idx < 512 * 16; idx += 256) {
      int l = idx >> 4, q = idx & 15;
      int pid = pidxl[l];
      if (pid >= i0 && pid < i0 + cN) out4[l * 16 + q] = w4[(pid - i0) * 16 + q];
    }
    __syncthreads();
  }
}

extern "C" void kernel_launch(void* const* d_in, const int* in_sizes, int n_in,
                              void* d_out, int out_size, void* d_ws, size_t ws_size,
                              hipStream_t stream) {
  const int* src  = (const int*)d_in[0];
  const int* dst  = (const int*)d_in[1];
  const float* w1 = (const float*)d_in[2];
  const float* b1 = (const float*)d_in[3];
  const float* w2 = (const float*)d_in[4];
  const float* b2 = (const float*)d_in[5];
  const float* Wq = (const float*)d_in[6];
  const float* Wk = (const float*)d_in[7];
  const float* Wv = (const float*)d_in[8];
  const float* Wo = (const float*)d_in[9];
  const float* bo = (const float*)d_in[10];
  const float* lng = (const float*)d_in[11];
  const float* lnb = (const float*)d_in[12];
  float* out = (float*)d_out;
  float* wsf = (float*)d_ws;
  int* wsi = (int*)d_ws;

  float* table = wsf + WS_TABLE;
  int* pidx  = wsi + WS_PIDX;
  int* pkey  = wsi + WS_PKEY;
  int* pmult = wsi + WS_PMULT;
  int* npair = wsi + WS_NPAIR;

  k_table<<<dim3(513), dim3(64), 0, stream>>>(w1, b1, w2, b2, table);
  k_dedup<<<dim3(256), dim3(256), 0, stream>>>(src, dst, pidx, pkey, pmult, npair);
  k_attn<<<dim3(512), dim3(256), 0, stream>>>(table, pidx, pkey, pmult, npair,
                                              Wq, Wk, Wv, Wo, bo, lng, lnb, out);
}